// Round 1
// baseline (342.335 us; speedup 1.0000x reference)
//
#include <hip/hip_runtime.h>
#include <hip/hip_bf16.h>

#define N_NODES 100000
#define H_DIM   128
#define N_RELS  90
#define N_BASES 4
#define N_EDGES 800000
#define SCAN_NB 391            // ceil(100000/256)
#define NBLK    6250           // N_NODES / 16

typedef __attribute__((ext_vector_type(8))) __bf16 bf16x8;
typedef __attribute__((ext_vector_type(4))) float  floatx4;

// ---- workspace layout (bytes); total ~7.73 MB ----
#define WT_OFF     0                           // Wt[o][c] 128*512 ushort = 131072
#define CNTS_OFF   131072                      // counts[100000] int = 400000
#define IDF_OFF    531072                      // identity-h flag, 4 B (memset with counts)
#define OFFS_OFF   531076                      // offsets[100000] int = 400000
#define CURS_OFF   931076                      // cursor[100000] int = 400000
#define BSUM_OFF   1331076                     // 391 int = 1564
#define RECS_OFF   1332640                     // recs[800000] u64 = 6400000 (8-aligned)
// end = 7732640

// ---------- helpers ----------
__device__ __forceinline__ float bs2f(unsigned short s) {
    union { unsigned u; float f; } x; x.u = ((unsigned)s) << 16; return x.f;
}
__device__ __forceinline__ unsigned short f2bs(float f) {
    unsigned u = __float_as_uint(f);
    return (unsigned short)((u + 0x7fffu + ((u >> 16) & 1u)) >> 16);   // RNE
}
template <int ISBF>
__device__ __forceinline__ float ldT(const void* p, size_t i) {
    if (ISBF) return bs2f(((const unsigned short*)p)[i]);
    return ((const float*)p)[i];
}

// ---------- 1: [merged] Wt repack + dst-degree count + h-identity check ----------
template <int ISBF>
__global__ __launch_bounds__(256) void prep_count_k(const void* __restrict__ weight,
                                                    unsigned short* __restrict__ wt,
                                                    const int* __restrict__ dst,
                                                    int* __restrict__ counts,
                                                    const int* __restrict__ h,
                                                    int* __restrict__ idflag) {
    int b = blockIdx.x;
    if (b < 256) {
        int tid = b * 256 + threadIdx.x;           // 65536 total
        int o = tid >> 9, c = tid & 511;
        int bb = c >> 7, i = c & 127;
        wt[tid] = f2bs(ldT<ISBF>(weight, (size_t)bb * 16384 + (size_t)i * 128 + o));
    } else {
        int e = (b - 256) * 256 + threadIdx.x;
        if (e < N_EDGES) atomicAdd(&counts[dst[e]], 1);
        if (e < N_NODES && h[e] != e) atomicOr(idflag, 1);
    }
}

// ---------- 2: CSR scan ----------
__global__ __launch_bounds__(256) void scanA(const int* __restrict__ counts,
                                             int* __restrict__ offs, int* __restrict__ bsum) {
    __shared__ int s[256];
    int t = threadIdx.x, i = blockIdx.x * 256 + t;
    int v = (i < N_NODES) ? counts[i] : 0;
    s[t] = v; __syncthreads();
    for (int off = 1; off < 256; off <<= 1) {
        int x = (t >= off) ? s[t - off] : 0;
        __syncthreads(); s[t] += x; __syncthreads();
    }
    if (i < N_NODES) offs[i] = s[t] - v;               // exclusive
    if (t == 255) bsum[blockIdx.x] = s[255];
}

__global__ __launch_bounds__(256) void scanC2(int* __restrict__ offs,
                                              const int* __restrict__ bsum,
                                              int* __restrict__ cursor) {
    int b = blockIdx.x, t = threadIdx.x;
    int v = 0;
    if (t < b) v = bsum[t];                     // SCAN_NB=391 < 512
    if (t + 256 < b) v += bsum[t + 256];
    v += __shfl_down(v, 32); v += __shfl_down(v, 16);
    v += __shfl_down(v, 8);  v += __shfl_down(v, 4);
    v += __shfl_down(v, 2);  v += __shfl_down(v, 1);
    __shared__ int wsum[4];
    __shared__ int sprefix;
    if ((t & 63) == 0) wsum[t >> 6] = v;
    __syncthreads();
    if (t == 0) sprefix = wsum[0] + wsum[1] + wsum[2] + wsum[3];
    __syncthreads();
    int i = b * 256 + t;
    if (i < N_NODES) {
        int o = offs[i] + sprefix;
        offs[i] = o; cursor[i] = o;
    }
}

// ---------- 3: fill 8B records {h[src]|rel<<20, norm fp32} sorted by dst ----------
template <int ISBF>
__global__ __launch_bounds__(256) void fill_k(const int* __restrict__ r, const void* __restrict__ norm,
                                              const int* __restrict__ src, const int* __restrict__ dst,
                                              const int* __restrict__ h, const int* __restrict__ idflag,
                                              int* __restrict__ cursor,
                                              unsigned long long* __restrict__ recs) {
    int e = blockIdx.x * 256 + threadIdx.x;
    if (e >= N_EDGES) return;
    float nm = ldT<ISBF>(norm, e);
    int s = src[e];
    int hs = (*idflag) ? h[s] : s;              // skip random h-gather when h==arange
    unsigned lo = (unsigned)hs | ((unsigned)r[e] << 20);   // h<2^20, rel<2^12
    unsigned long long rc = (unsigned long long)lo
                          | ((unsigned long long)__float_as_uint(nm) << 32);
    int pos = atomicAdd(&cursor[dst[e]], 1);
    recs[pos] = rc;                             // plain store: L2 merges bucket-local writes
}

// ---------- 4: fused gather-aggregate + MFMA basis GEMM, dtype-specialized ----------
// Phase1 (slot-per-dst): wave w, slot g=lane>>4 owns dst blk*16+w*4+g; j=lane&15
// covers channels j*8..j*8+7 (16B row loads).
// NEW: register double-buffered row pipeline — rows(k+4) are issued from the
// already-arrived rec prefetch BEFORE consuming rows(k), so one consume phase
// (~450 cy VALU) overlaps the gather miss latency. Costs ~+40 VGPR (cap drops
// to ~16 waves/CU ~= measured residency, so no real occupancy loss).
template <int ISBF>
__global__ __launch_bounds__(256) void fused_k(const int* __restrict__ counts,
                                               const int* __restrict__ offs,
                                               const unsigned long long* __restrict__ recs,
                                               const void* __restrict__ emb,
                                               const unsigned short* __restrict__ wt,
                                               const void* __restrict__ bias,
                                               const void* __restrict__ wcomp,
                                               void* __restrict__ out) {
    __shared__ float wc[N_RELS * 4];                      // 1440 B
    __shared__ __align__(16) unsigned short y[16][520];
    // 360 > 256: MUST stride (R5 bug)
    for (int t = threadIdx.x; t < N_RELS * 4; t += 256) wc[t] = ldT<ISBF>(wcomp, t);
    __syncthreads();

    int t = threadIdx.x;
    int lane = t & 63;
    int w = t >> 6;
    int g = lane >> 4, j = lane & 15;
    int blk = blockIdx.x;
    int dloc = w * 4 + g;
    int d = blk * 16 + dloc;
    int deg = counts[d], start = offs[d];
    float inv = 1.0f / (float)(deg > 1 ? deg : 1);

    float acc[4][8];
#pragma unroll
    for (int b = 0; b < 4; ++b)
#pragma unroll
        for (int c = 0; c < 8; ++c) acc[b][c] = 0.f;

    // wave-uniform loop bound = max deg over the wave's 4 slots
    int kmax = __shfl(deg, 0);
    kmax = max(kmax, __shfl(deg, 16));
    kmax = max(kmax, __shfl(deg, 32));
    kmax = max(kmax, __shfl(deg, 48));

    unsigned long long rcur[4], rnext[4], rfut[4];
    bf16x8  rbA[4], rbB[4];
    floatx4 rfA[4][2], rfB[4][2];

#define LOADRECS(DST, KB)                                                     \
    do {                                                                      \
        _Pragma("unroll") for (int u = 0; u < 4; ++u) {                       \
            int kk = (KB) + u;                                                \
            DST[u] = recs[(kk < deg) ? start + kk : 0];                       \
        }                                                                     \
    } while (0)

#define LOADROWS(RB, RF, RV)                                                  \
    do {                                                                      \
        if (ISBF) {                                                           \
            _Pragma("unroll") for (int u = 0; u < 4; ++u) {                   \
                unsigned hx = (unsigned)RV[u] & 0xFFFFFu;                     \
                RB[u] = *(const bf16x8*)((const unsigned short*)emb           \
                                         + (size_t)hx * 128 + j * 8);         \
            }                                                                 \
        } else {                                                              \
            _Pragma("unroll") for (int u = 0; u < 4; ++u) {                   \
                unsigned hx = (unsigned)RV[u] & 0xFFFFFu;                     \
                const floatx4* f = (const floatx4*)((const float*)emb         \
                                         + (size_t)hx * 128 + j * 8);         \
                RF[u][0] = f[0]; RF[u][1] = f[1];                             \
            }                                                                 \
        }                                                                     \
    } while (0)

#define CONSUME(RB, RF, RV, KB)                                               \
    do {                                                                      \
        _Pragma("unroll") for (int u = 0; u < 4; ++u) {                       \
            bool vld = ((KB) + u) < deg;                                      \
            unsigned rel = ((unsigned)RV[u] >> 20) & 0xFFFu;                  \
            float nm = vld ? __uint_as_float((unsigned)(RV[u] >> 32)) : 0.f;  \
            const float* cw = &wc[rel * 4];                                   \
            float c0 = cw[0]*nm, c1 = cw[1]*nm, c2 = cw[2]*nm, c3 = cw[3]*nm; \
            float x[8];                                                       \
            if (ISBF) {                                                       \
                _Pragma("unroll") for (int c = 0; c < 8; ++c)                 \
                    x[c] = (float)RB[u][c];                                   \
            } else {                                                          \
                _Pragma("unroll") for (int c = 0; c < 4; ++c) {               \
                    x[c] = RF[u][0][c]; x[c + 4] = RF[u][1][c];               \
                }                                                             \
            }                                                                 \
            _Pragma("unroll") for (int c = 0; c < 8; ++c) {                   \
                acc[0][c] += c0 * x[c]; acc[1][c] += c1 * x[c];               \
                acc[2][c] += c2 * x[c]; acc[3][c] += c3 * x[c];               \
            }                                                                 \
        }                                                                     \
    } while (0)

    // prologue: rows(0) in flight, recs(4) in flight
    LOADRECS(rcur, 0);
    LOADROWS(rbA, rfA, rcur);
    LOADRECS(rnext, 4);

    for (int k = 0; k < kmax; k += 8) {
        // rows(k+4) issued BEFORE consuming rows(k) -> consume overlaps flight
        LOADROWS(rbB, rfB, rnext);
        LOADRECS(rfut, k + 8);
        CONSUME(rbA, rfA, rcur, k);
#pragma unroll
        for (int u = 0; u < 4; ++u) { rcur[u] = rnext[u]; rnext[u] = rfut[u]; }
        if (k + 4 >= kmax) break;
        LOADROWS(rbA, rfA, rnext);          // rows(k+8) from recs(k+8)
        LOADRECS(rfut, k + 12);
        CONSUME(rbB, rfB, rcur, k + 4);
#pragma unroll
        for (int u = 0; u < 4; ++u) { rcur[u] = rnext[u]; rnext[u] = rfut[u]; }
    }
#undef LOADRECS
#undef LOADROWS
#undef CONSUME

    // scale + pack to LDS: y[dloc][b*128 + j*8 .. +7]
#pragma unroll
    for (int b = 0; b < 4; ++b) {
        union { unsigned short u[8]; uint4 v; } pk;
#pragma unroll
        for (int c = 0; c < 8; ++c) pk.u[c] = f2bs(acc[b][c] * inv);
        *(uint4*)&y[dloc][b * 128 + j * 8] = pk.v;
    }
    __syncthreads();

    // ---- phase 2: out[16 dsts][128] = y[16][512] x Wt^T, MFMA 16x16x32 ----
    int m = lane & 15;          // A row (dst) / B col (o) within tile
    int q = lane >> 4;          // quad
    for (int half = 0; half < 2; ++half) {
        int ct = w * 2 + half;                   // col-tile 0..7
        floatx4 accm = {0.f, 0.f, 0.f, 0.f};
        const unsigned short* bp = wt + (size_t)(ct * 16 + m) * 512 + q * 8;
#pragma unroll
        for (int kc = 0; kc < 16; ++kc) {
            bf16x8 af = *(const bf16x8*)&y[m][kc * 32 + q * 8];
            bf16x8 bf = *(const bf16x8*)(bp + kc * 32);
            accm = __builtin_amdgcn_mfma_f32_16x16x32_bf16(af, bf, accm, 0, 0, 0);
        }
#pragma unroll
        for (int v = 0; v < 4; ++v) {            // C/D: row(dst)=q*4+v, col(o)=ct*16+m
            int o = ct * 16 + m;
            float val = accm[v] + ldT<ISBF>(bias, o);
            size_t oi = (size_t)(blk * 16 + q * 4 + v) * H_DIM + o;
            // plain stores: line written by 4 waves of the same block -> L2 merges
            if (ISBF) ((unsigned short*)out)[oi] = f2bs(val);
            else      ((float*)out)[oi] = val;
        }
    }
}

template <int ISBF>
static void launch_all(const int* h, const int* r, const void* norm, const int* src,
                       const int* dst, const void* emb, const void* weight,
                       const void* wcomp, const void* bias, char* ws, void* d_out,
                       hipStream_t stream) {
    unsigned short*     wt     = (unsigned short*)(ws + WT_OFF);
    int*                counts = (int*)(ws + CNTS_OFF);
    int*                idflag = (int*)(ws + IDF_OFF);
    int*                offs   = (int*)(ws + OFFS_OFF);
    int*                cursor = (int*)(ws + CURS_OFF);
    int*                bsum   = (int*)(ws + BSUM_OFF);
    unsigned long long* recs   = (unsigned long long*)(ws + RECS_OFF);

    hipMemsetAsync(counts, 0, N_NODES * sizeof(int) + sizeof(int), stream); // counts + idflag

    prep_count_k<ISBF><<<256 + (N_EDGES + 255) / 256, 256, 0, stream>>>(weight, wt, dst,
                                                                        counts, h, idflag);
    scanA<<<SCAN_NB, 256, 0, stream>>>(counts, offs, bsum);
    scanC2<<<SCAN_NB, 256, 0, stream>>>(offs, bsum, cursor);
    fill_k<ISBF><<<(N_EDGES + 255) / 256, 256, 0, stream>>>(r, norm, src, dst, h, idflag,
                                                            cursor, recs);
    fused_k<ISBF><<<NBLK, 256, 0, stream>>>(counts, offs, recs, emb, wt, bias, wcomp, d_out);
}

extern "C" void kernel_launch(void* const* d_in, const int* in_sizes, int n_in,
                              void* d_out, int out_size, void* d_ws, size_t ws_size,
                              hipStream_t stream) {
    const int*  h      = (const int*)d_in[0];
    const int*  r      = (const int*)d_in[1];
    const void* norm   = d_in[2];
    const int*  src    = (const int*)d_in[3];
    const int*  dst    = (const int*)d_in[4];
    const void* emb    = d_in[5];
    const void* weight = d_in[6];
    const void* wcomp  = d_in[7];
    const void* bias   = d_in[8];
    char* ws = (char*)d_ws;

    // host-side dtype dispatch: norm is [E,1]; bf16 -> 1.6 MB, f32 -> 3.2 MB
    int isbf = (in_sizes[2] == (int)(N_EDGES * sizeof(unsigned short))) ? 1 : 0;

    if (isbf) launch_all<1>(h, r, norm, src, dst, emb, weight, wcomp, bias, ws, d_out, stream);
    else      launch_all<0>(h, r, norm, src, dst, emb, weight, wcomp, bias, ws, d_out, stream);
}